// Round 1
// baseline (355.877 us; speedup 1.0000x reference)
//
#include <hip/hip_runtime.h>
#include <hip/hip_bf16.h>
#include <cstdint>
#include <cstddef>

// Problem: B=32, C=768, H=W=32 (HW=1024).
// out[b,c,hw] = (0.5 + 0.5 * cos_gate(b,c)) * X[b,c,hw]
// cos_gate = dot(K_c,V_c)/((||K_c||+1e-12)(||V_c||+1e-12)),
// K = Wk @ Xn, V = Wv @ Xn (rows [0,768) and [768,1536) of W_in; Q rows unused),
// Xn = X * rsqrt(mean_c X^2 + 1e-6).

#define B_   32
#define C_   768
#define HW_  1024
#define CHW_ (C_ * HW_)          // 786432
#define EPS_NORM 1e-6f
#define EPS_COS  1e-12f

using f32x4  = __attribute__((ext_vector_type(4))) float;
using bf16x8 = __attribute__((ext_vector_type(8))) short;   // 8 bf16 = 4 VGPRs

__device__ inline unsigned short f2bf(float f) {
    union { float f; unsigned u; } v; v.f = f;
    unsigned u = v.u;
    u += 0x7fffu + ((u >> 16) & 1u);        // round-to-nearest-even
    return (unsigned short)(u >> 16);
}

// ---------------------------------------------------------------------------
// K1: partial channel sum-of-squares -> ssum[b*HW+hw] (atomic accumulate).
// grid (6 c-chunks, 4 hw-chunks, 32 b), block 256. Coalesced along hw.
// ---------------------------------------------------------------------------
__global__ void sumsq_kernel(const float* __restrict__ X, float* __restrict__ ssum) {
    const int b  = blockIdx.z;
    const int hw = blockIdx.y * 256 + threadIdx.x;
    const int c0 = blockIdx.x * 128;
    const float* xp = X + (size_t)b * CHW_ + (size_t)c0 * HW_ + hw;
    float s = 0.f;
    #pragma unroll 8
    for (int c = 0; c < 128; ++c) {
        float v = xp[(size_t)c * HW_];
        s += v * v;
    }
    atomicAdd(&ssum[b * HW_ + hw], s);
}

// ---------------------------------------------------------------------------
// K2: cast first 1536 rows of W_in (fp32) -> bf16. 1536*768 elems, 4/thread.
// ---------------------------------------------------------------------------
__global__ void wconv_kernel(const float* __restrict__ W, unsigned short* __restrict__ Wbf) {
    const int i = blockIdx.x * 256 + threadIdx.x;     // quad index, 0..294911
    const float4 v = reinterpret_cast<const float4*>(W)[i];
    ushort4 o;
    o.x = f2bf(v.x); o.y = f2bf(v.y); o.z = f2bf(v.z); o.w = f2bf(v.w);
    reinterpret_cast<ushort4*>(Wbf)[i] = o;
}

// ---------------------------------------------------------------------------
// K3: Xn_t[b][hw][c] = bf16( X[b][c][hw] * rsqrt(ssum/768 + eps) )
// 64x64 tile transpose through LDS so the GEMM's B operand is k-contiguous.
// grid (16 hw-tiles, 12 c-tiles, 32 b), block 256.
// ---------------------------------------------------------------------------
__global__ void xnt_kernel(const float* __restrict__ X, const float* __restrict__ ssum,
                           unsigned short* __restrict__ Xnt) {
    const int b   = blockIdx.z;
    const int c0  = blockIdx.y * 64;
    const int hw0 = blockIdx.x * 64;
    const int tid = threadIdx.x;
    __shared__ short T[64][72];   // +8 pad: row stride 144 B, benign conflicts

    #pragma unroll
    for (int it = 0; it < 4; ++it) {
        int q  = it * 256 + tid;        // 0..1023
        int r  = q >> 4;                // c row in tile
        int c4 = (q & 15) * 4;          // hw col in tile
        const float4 x = *reinterpret_cast<const float4*>(
            X + (size_t)b * CHW_ + (size_t)(c0 + r) * HW_ + hw0 + c4);
        const float4 s = *reinterpret_cast<const float4*>(ssum + b * HW_ + hw0 + c4);
        ushort4 o;
        o.x = f2bf(x.x * rsqrtf(s.x * (1.f / 768.f) + EPS_NORM));
        o.y = f2bf(x.y * rsqrtf(s.y * (1.f / 768.f) + EPS_NORM));
        o.z = f2bf(x.z * rsqrtf(s.z * (1.f / 768.f) + EPS_NORM));
        o.w = f2bf(x.w * rsqrtf(s.w * (1.f / 768.f) + EPS_NORM));
        *reinterpret_cast<ushort4*>(&T[r][c4]) = o;
    }
    __syncthreads();
    #pragma unroll
    for (int it = 0; it < 2; ++it) {
        int q  = it * 256 + tid;        // 0..511
        int rp = q >> 3;                // hw row
        int cc = (q & 7) * 8;           // c chunk
        __align__(16) unsigned short tmp[8];
        #pragma unroll
        for (int j = 0; j < 8; ++j) tmp[j] = (unsigned short)T[cc + j][rp];
        *reinterpret_cast<uint4*>(
            Xnt + (size_t)b * CHW_ + (size_t)(hw0 + rp) * C_ + c0 + cc) =
            *reinterpret_cast<const uint4*>(tmp);
    }
}

// ---------------------------------------------------------------------------
// K4: dual-tile GEMM + fused row reductions.
// Block = 128 c-rows x 128 hw-cols of BOTH K and V (shared B stage).
// Per c-row accumulate: dot(K,V), ||K||^2, ||V||^2 over this hw tile,
// atomicAdd into wsA[(b*768+c)*3 + {0,1,2}].
// grid (8 hw-tiles, 6 c-tiles, 32 b), block 256 (4 waves, 64x64 quadrant each).
// ---------------------------------------------------------------------------
__global__ __launch_bounds__(256, 2) void gemm_kernel(
        const unsigned short* __restrict__ Wbf,   // [1536][768] bf16
        const unsigned short* __restrict__ Xnt,   // [B][HW][C] bf16
        float* __restrict__ wsA) {
    const int n0   = blockIdx.x * 128;
    const int c0   = blockIdx.y * 128;
    const int b    = blockIdx.z;
    const int tid  = threadIdx.x;
    const int lane = tid & 63;
    const int wave = tid >> 6;
    const int wm   = (wave >> 1) * 64;
    const int wn   = (wave & 1) * 64;
    const int quad = lane >> 4;
    const int l15  = lane & 15;

    // row stride 40 shorts = 80 B = 20 banks -> only 2-way aliasing (free),
    // and 16 B alignment preserved for ds_read_b128.
    __shared__ short sAK[128][40];
    __shared__ short sAV[128][40];
    __shared__ short sB [128][40];

    const f32x4 zero = {0.f, 0.f, 0.f, 0.f};
    f32x4 accK[4][4], accV[4][4];
    #pragma unroll
    for (int i = 0; i < 4; ++i)
        #pragma unroll
        for (int j = 0; j < 4; ++j) { accK[i][j] = zero; accV[i][j] = zero; }

    const size_t wk_base = (size_t)c0 * 768;
    const size_t wv_base = (size_t)(768 + c0) * 768;
    const size_t xb      = (size_t)b * CHW_ + (size_t)n0 * 768;

    for (int k0 = 0; k0 < 768; k0 += 32) {
        __syncthreads();
        // stage: 128 rows x 32 k, bf16, 16 B per load; same shape for all three
        #pragma unroll
        for (int it = 0; it < 2; ++it) {
            int chunk = it * 256 + tid;          // 0..511
            int r  = chunk >> 2;                 // 0..127
            int kk = (chunk & 3) * 8;            // 0,8,16,24
            uint4 vk = *reinterpret_cast<const uint4*>(Wbf + wk_base + (size_t)r * 768 + k0 + kk);
            *reinterpret_cast<uint4*>(&sAK[r][kk]) = vk;
            uint4 vv = *reinterpret_cast<const uint4*>(Wbf + wv_base + (size_t)r * 768 + k0 + kk);
            *reinterpret_cast<uint4*>(&sAV[r][kk]) = vv;
            uint4 vb = *reinterpret_cast<const uint4*>(Xnt + xb + (size_t)r * 768 + k0 + kk);
            *reinterpret_cast<uint4*>(&sB[r][kk]) = vb;
        }
        __syncthreads();

        bf16x8 aK[4], aV[4], bF[4];
        #pragma unroll
        for (int i = 0; i < 4; ++i) {
            aK[i] = *reinterpret_cast<const bf16x8*>(&sAK[wm + 16 * i + l15][quad * 8]);
            aV[i] = *reinterpret_cast<const bf16x8*>(&sAV[wm + 16 * i + l15][quad * 8]);
            bF[i] = *reinterpret_cast<const bf16x8*>(&sB [wn + 16 * i + l15][quad * 8]);
        }
        #pragma unroll
        for (int i = 0; i < 4; ++i)
            #pragma unroll
            for (int j = 0; j < 4; ++j) {
                accK[i][j] = __builtin_amdgcn_mfma_f32_16x16x32_bf16(aK[i], bF[j], accK[i][j], 0, 0, 0);
                accV[i][j] = __builtin_amdgcn_mfma_f32_16x16x32_bf16(aV[i], bF[j], accV[i][j], 0, 0, 0);
            }
    }

    // epilogue: per (i,r) is one c-row (per quad); sum over the 64 hw cols
    // this wave owns (4 j-frags x 16 col-lanes), then atomic into wsA.
    #pragma unroll
    for (int i = 0; i < 4; ++i) {
        #pragma unroll
        for (int r = 0; r < 4; ++r) {
            float pd = 0.f, pk = 0.f, pv = 0.f;
            #pragma unroll
            for (int j = 0; j < 4; ++j) {
                float kk = accK[i][j][r], vv = accV[i][j][r];
                pd += kk * vv; pk += kk * kk; pv += vv * vv;
            }
            #pragma unroll
            for (int off = 1; off < 16; off <<= 1) {
                pd += __shfl_xor(pd, off);
                pk += __shfl_xor(pk, off);
                pv += __shfl_xor(pv, off);
            }
            if (l15 == 0) {
                int c = c0 + wm + 16 * i + 4 * quad + r;
                float* dst = wsA + ((size_t)b * C_ + c) * 3;
                atomicAdd(dst + 0, pd);
                atomicAdd(dst + 1, pk);
                atomicAdd(dst + 2, pv);
            }
        }
    }
}

// ---------------------------------------------------------------------------
// K5: out = X * (0.5 + 0.5 * dot/((||K||+eps)(||V||+eps))), float4.
// ---------------------------------------------------------------------------
__global__ void final_kernel(const float* __restrict__ X, const float* __restrict__ wsA,
                             float* __restrict__ out) {
    const int i4 = blockIdx.x * 256 + threadIdx.x;   // 0..6291455
    const size_t e = (size_t)i4 * 4;
    const int b = (int)(e / CHW_);
    const int c = (int)((e >> 10) % C_);
    const float* a = wsA + ((size_t)b * C_ + c) * 3;
    const float pd = a[0], pk = a[1], pv = a[2];
    const float A = pd / ((sqrtf(pk) + EPS_COS) * (sqrtf(pv) + EPS_COS));
    const float g = 0.5f * A + 0.5f;
    float4 x = reinterpret_cast<const float4*>(X)[i4];
    float4 o;
    o.x = x.x * g; o.y = x.y * g; o.z = x.z * g; o.w = x.w * g;
    reinterpret_cast<float4*>(out)[i4] = o;
}

// ---------------------------------------------------------------------------
extern "C" void kernel_launch(void* const* d_in, const int* in_sizes, int n_in,
                              void* d_out, int out_size, void* d_ws, size_t ws_size,
                              hipStream_t stream) {
    const float* X = (const float*)d_in[0];   // [32,768,32,32]
    const float* W = (const float*)d_in[1];   // [2304,768]
    float* out = (float*)d_out;

    // workspace layout (bytes):
    //   [0,        294912)  wsA   float[32*768*3]  (dot, nk2, nv2)
    //   [294912,   425984)  ssum  float[32*1024]
    //   [425984,  2785280)  Wbf   bf16[1536*768]
    //   [2785280, 53116928) Xnt   bf16[32][1024][768]
    char* ws = (char*)d_ws;
    float* wsA           = (float*)ws;
    float* ssum          = (float*)(ws + 294912);
    unsigned short* Wbf  = (unsigned short*)(ws + 425984);
    unsigned short* Xnt  = (unsigned short*)(ws + 2785280);

    hipMemsetAsync(ws, 0, 425984, stream);   // zero wsA + ssum (harness poisons ws)

    sumsq_kernel<<<dim3(6, 4, 32),   256, 0, stream>>>(X, ssum);
    wconv_kernel<<<dim3(1152),       256, 0, stream>>>(W, Wbf);
    xnt_kernel  <<<dim3(16, 12, 32), 256, 0, stream>>>(X, ssum, Xnt);
    gemm_kernel <<<dim3(8, 6, 32),   256, 0, stream>>>(Wbf, Xnt, wsA);
    final_kernel<<<dim3(24576),      256, 0, stream>>>(X, wsA, out);
}

// Round 2
// 349.826 us; speedup vs baseline: 1.0173x; 1.0173x over previous
//
#include <hip/hip_runtime.h>
#include <hip/hip_bf16.h>
#include <cstdint>
#include <cstddef>

// Problem: B=32, C=768, H=W=32 (HW=1024).
// out[b,c,hw] = (0.5 + 0.5 * cos_gate(b,c)) * X[b,c,hw]
// cos_gate = dot(K_c,V_c)/((||K_c||+1e-12)(||V_c||+1e-12)),
// K = Wk @ Xn, V = Wv @ Xn (rows [0,768) and [768,1536) of W_in; Q rows unused),
// Xn = X * rsqrt(mean_c X^2 + 1e-6).

#define B_   32
#define C_   768
#define HW_  1024
#define CHW_ (C_ * HW_)          // 786432
#define EPS_NORM 1e-6f
#define EPS_COS  1e-12f

using f32x4  = __attribute__((ext_vector_type(4))) float;
using bf16x8 = __attribute__((ext_vector_type(8))) short;   // 8 bf16 = 4 VGPRs

__device__ inline unsigned short f2bf(float f) {
    union { float f; unsigned u; } v; v.f = f;
    unsigned u = v.u;
    u += 0x7fffu + ((u >> 16) & 1u);        // round-to-nearest-even
    return (unsigned short)(u >> 16);
}

// async global->LDS, 16 B per lane. LDS dst is wave-uniform base + lane*16.
__device__ __forceinline__ void load16_lds(const unsigned short* g, short* l) {
    __builtin_amdgcn_global_load_lds(
        (const __attribute__((address_space(1))) unsigned int*)g,
        (__attribute__((address_space(3))) unsigned int*)l,
        16, 0, 0);
}

// ---------------------------------------------------------------------------
// K1: cast first 1536 rows of W_in (fp32) -> bf16. 1536*768 elems, 4/thread.
// ---------------------------------------------------------------------------
__global__ void wconv_kernel(const float* __restrict__ W, unsigned short* __restrict__ Wbf) {
    const int i = blockIdx.x * 256 + threadIdx.x;     // quad index, 0..294911
    const float4 v = reinterpret_cast<const float4*>(W)[i];
    ushort4 o;
    o.x = f2bf(v.x); o.y = f2bf(v.y); o.z = f2bf(v.z); o.w = f2bf(v.w);
    reinterpret_cast<ushort4*>(Wbf)[i] = o;
}

// ---------------------------------------------------------------------------
// K2 (fused): per (b, 64-hw tile): sumsq over all C -> rstd (in-block),
// then normalize + bf16 cast + 64x64 LDS transpose -> Xnt[b][hw][c].
// grid (16 hw-tiles, 32 b), block 256.
// ---------------------------------------------------------------------------
__global__ __launch_bounds__(256) void normxnt_kernel(const float* __restrict__ X,
                                                      unsigned short* __restrict__ Xnt) {
    const int b   = blockIdx.y;
    const int hw0 = blockIdx.x * 64;
    const int tid = threadIdx.x;

    __shared__ float red[4][64];
    __shared__ float rstd[64];
    __shared__ short T[64][72];   // +8 pad for transpose phase

    // pass 1: channel sum-of-squares for this block's 64 hw positions
    {
        const int hwl = tid & 63;
        const int cp  = tid >> 6;          // 4 c-partitions of 192
        const float* xp = X + (size_t)b * CHW_ + (size_t)(cp * 192) * HW_ + hw0 + hwl;
        float s = 0.f;
        #pragma unroll 8
        for (int c = 0; c < 192; ++c) {
            float v = xp[(size_t)c * HW_];
            s += v * v;
        }
        red[cp][hwl] = s;
    }
    __syncthreads();
    if (tid < 64) {
        float t = red[0][tid] + red[1][tid] + red[2][tid] + red[3][tid];
        rstd[tid] = rsqrtf(t * (1.f / 768.f) + EPS_NORM);
    }
    __syncthreads();

    // pass 2: normalize + cast + transpose, 12 c-tiles of 64 (re-read hits L2/L3)
    for (int ct = 0; ct < 12; ++ct) {
        const int c0 = ct * 64;
        #pragma unroll
        for (int it = 0; it < 4; ++it) {
            int q  = it * 256 + tid;        // 0..1023
            int r  = q >> 4;                // c row in tile
            int c4 = (q & 15) * 4;          // hw col in tile
            const float4 x = *reinterpret_cast<const float4*>(
                X + (size_t)b * CHW_ + (size_t)(c0 + r) * HW_ + hw0 + c4);
            ushort4 o;
            o.x = f2bf(x.x * rstd[c4 + 0]);
            o.y = f2bf(x.y * rstd[c4 + 1]);
            o.z = f2bf(x.z * rstd[c4 + 2]);
            o.w = f2bf(x.w * rstd[c4 + 3]);
            *reinterpret_cast<ushort4*>(&T[r][c4]) = o;
        }
        __syncthreads();
        #pragma unroll
        for (int it = 0; it < 2; ++it) {
            int q  = it * 256 + tid;        // 0..511
            int rp = q >> 3;                // hw row
            int cc = (q & 7) * 8;           // c chunk
            __align__(16) unsigned short tmp[8];
            #pragma unroll
            for (int j = 0; j < 8; ++j) tmp[j] = (unsigned short)T[cc + j][rp];
            *reinterpret_cast<uint4*>(
                Xnt + (size_t)b * CHW_ + (size_t)(hw0 + rp) * C_ + c0 + cc) =
                *reinterpret_cast<const uint4*>(tmp);
        }
        __syncthreads();
    }
}

// ---------------------------------------------------------------------------
// K3: dual-tile GEMM + fused row reductions (m97-style staging).
// Block = 128 c-rows x 128 hw-cols of BOTH K and V (shared B stage).
// global_load_lds width=16 staging; unpadded 64 B LDS rows with XOR chunk
// swizzle: chunk c of row r lives at slot c ^ ((r>>1)&3)  -> 2-way bank
// aliasing on ds_read_b128 fragments (free per m136).
// Per c-row accumulate dot/||K||^2/||V||^2 over hw tile -> atomicAdd wsA.
// grid (8 hw-tiles, 6 c-tiles, 32 b), block 256.
// ---------------------------------------------------------------------------
__global__ __launch_bounds__(256, 2) void gemm_kernel(
        const unsigned short* __restrict__ Wbf,   // [1536][768] bf16
        const unsigned short* __restrict__ Xnt,   // [B][HW][C] bf16
        float* __restrict__ wsA) {
    const int n0   = blockIdx.x * 128;
    const int c0   = blockIdx.y * 128;
    const int b    = blockIdx.z;
    const int tid  = threadIdx.x;
    const int lane = tid & 63;
    const int wave = tid >> 6;
    const int wm   = (wave >> 1) * 64;
    const int wn   = (wave & 1) * 64;
    const int quad = lane >> 4;
    const int l15  = lane & 15;

    __shared__ short sAK[128][32];
    __shared__ short sAV[128][32];
    __shared__ short sB [128][32];

    const f32x4 zero = {0.f, 0.f, 0.f, 0.f};
    f32x4 accK[4][4], accV[4][4];
    #pragma unroll
    for (int i = 0; i < 4; ++i)
        #pragma unroll
        for (int j = 0; j < 4; ++j) { accK[i][j] = zero; accV[i][j] = zero; }

    const size_t wk_base = (size_t)c0 * 768;
    const size_t wv_base = (size_t)(768 + c0) * 768;
    const size_t xb      = (size_t)b * CHW_ + (size_t)n0 * 768;

    // staging lane->(row,chunk) mapping, constant across k-steps
    const int slot0   = tid;            // it=0
    const int row0    = slot0 >> 2;
    const int chunk0  = (slot0 & 3) ^ ((row0 >> 1) & 3);
    const int slot1   = 256 + tid;      // it=1
    const int row1    = slot1 >> 2;
    const int chunk1  = (slot1 & 3) ^ ((row1 >> 1) & 3);
    const int ldsrow0 = wave * 16;      // wave-uniform LDS base rows
    const int ldsrow1 = 64 + wave * 16;
    const size_t goff0 = (size_t)row0 * 768 + chunk0 * 8;
    const size_t goff1 = (size_t)row1 * 768 + chunk1 * 8;

    for (int k0 = 0; k0 < 768; k0 += 32) {
        __syncthreads();
        load16_lds(Wbf + wk_base + goff0 + k0, &sAK[ldsrow0][0]);
        load16_lds(Wbf + wv_base + goff0 + k0, &sAV[ldsrow0][0]);
        load16_lds(Xnt + xb      + goff0 + k0, &sB [ldsrow0][0]);
        load16_lds(Wbf + wk_base + goff1 + k0, &sAK[ldsrow1][0]);
        load16_lds(Wbf + wv_base + goff1 + k0, &sAV[ldsrow1][0]);
        load16_lds(Xnt + xb      + goff1 + k0, &sB [ldsrow1][0]);
        __syncthreads();

        bf16x8 aK[4], aV[4], bF[4];
        #pragma unroll
        for (int i = 0; i < 4; ++i) {
            const int rA = wm + 16 * i + l15;
            const int oA = ((((rA >> 1) & 3) ^ quad)) * 8;
            aK[i] = *reinterpret_cast<const bf16x8*>(&sAK[rA][oA]);
            aV[i] = *reinterpret_cast<const bf16x8*>(&sAV[rA][oA]);
            const int rB = wn + 16 * i + l15;
            const int oB = ((((rB >> 1) & 3) ^ quad)) * 8;
            bF[i] = *reinterpret_cast<const bf16x8*>(&sB[rB][oB]);
        }
        #pragma unroll
        for (int i = 0; i < 4; ++i)
            #pragma unroll
            for (int j = 0; j < 4; ++j) {
                accK[i][j] = __builtin_amdgcn_mfma_f32_16x16x32_bf16(aK[i], bF[j], accK[i][j], 0, 0, 0);
                accV[i][j] = __builtin_amdgcn_mfma_f32_16x16x32_bf16(aV[i], bF[j], accV[i][j], 0, 0, 0);
            }
    }

    // epilogue: per (i,r) is one c-row (per quad); reduce over the 64 hw cols
    // this wave owns (4 j-frags x 16 col-lanes), then atomic into wsA.
    #pragma unroll
    for (int i = 0; i < 4; ++i) {
        #pragma unroll
        for (int r = 0; r < 4; ++r) {
            float pd = 0.f, pk = 0.f, pv = 0.f;
            #pragma unroll
            for (int j = 0; j < 4; ++j) {
                float kk = accK[i][j][r], vv = accV[i][j][r];
                pd += kk * vv; pk += kk * kk; pv += vv * vv;
            }
            #pragma unroll
            for (int off = 1; off < 16; off <<= 1) {
                pd += __shfl_xor(pd, off);
                pk += __shfl_xor(pk, off);
                pv += __shfl_xor(pv, off);
            }
            if (l15 == 0) {
                int c = c0 + wm + 16 * i + 4 * quad + r;
                float* dst = wsA + ((size_t)b * C_ + c) * 3;
                atomicAdd(dst + 0, pd);
                atomicAdd(dst + 1, pk);
                atomicAdd(dst + 2, pv);
            }
        }
    }
}

// ---------------------------------------------------------------------------
// K4: out = X * (0.5 + 0.5 * dot/((||K||+eps)(||V||+eps))), float4.
// ---------------------------------------------------------------------------
__global__ void final_kernel(const float* __restrict__ X, const float* __restrict__ wsA,
                             float* __restrict__ out) {
    const int i4 = blockIdx.x * 256 + threadIdx.x;   // 0..6291455
    const size_t e = (size_t)i4 * 4;
    const int b = (int)(e / CHW_);
    const int c = (int)((e >> 10) % C_);
    const float* a = wsA + ((size_t)b * C_ + c) * 3;
    const float pd = a[0], pk = a[1], pv = a[2];
    const float A = pd / ((sqrtf(pk) + EPS_COS) * (sqrtf(pv) + EPS_COS));
    const float g = 0.5f * A + 0.5f;
    float4 x = reinterpret_cast<const float4*>(X)[i4];
    float4 o;
    o.x = x.x * g; o.y = x.y * g; o.z = x.z * g; o.w = x.w * g;
    reinterpret_cast<float4*>(out)[i4] = o;
}

// ---------------------------------------------------------------------------
extern "C" void kernel_launch(void* const* d_in, const int* in_sizes, int n_in,
                              void* d_out, int out_size, void* d_ws, size_t ws_size,
                              hipStream_t stream) {
    const float* X = (const float*)d_in[0];   // [32,768,32,32]
    const float* W = (const float*)d_in[1];   // [2304,768]
    float* out = (float*)d_out;

    // workspace layout (bytes):
    //   [0,       294912)   wsA   float[32*768*3]  (dot, nk2, nv2)
    //   [294912,  2654208)  Wbf   bf16[1536*768]
    //   [2654208, 52985856) Xnt   bf16[32][1024][768]
    char* ws = (char*)d_ws;
    float* wsA           = (float*)ws;
    unsigned short* Wbf  = (unsigned short*)(ws + 294912);
    unsigned short* Xnt  = (unsigned short*)(ws + 2654208);

    hipMemsetAsync(wsA, 0, 294912, stream);   // zero atomic accumulators

    wconv_kernel  <<<dim3(1152),      256, 0, stream>>>(W, Wbf);
    normxnt_kernel<<<dim3(16, 32),    256, 0, stream>>>(X, Xnt);
    gemm_kernel   <<<dim3(8, 6, 32),  256, 0, stream>>>(Wbf, Xnt, wsA);
    final_kernel  <<<dim3(24576),     256, 0, stream>>>(X, wsA, out);
}

// Round 3
// 335.202 us; speedup vs baseline: 1.0617x; 1.0436x over previous
//
#include <hip/hip_runtime.h>
#include <hip/hip_bf16.h>
#include <cstdint>
#include <cstddef>

// Problem: B=32, C=768, H=W=32 (HW=1024).
// out[b,c,hw] = (0.5 + 0.5 * cos_gate(b,c)) * X[b,c,hw]
// cos_gate = dot(K_c,V_c)/((||K_c||+1e-12)(||V_c||+1e-12)),
// K = Wk @ Xn, V = Wv @ Xn (rows [0,768) / [768,1536) of W_in; Q rows unused),
// Xn = X * rsqrt(mean_c X^2 + 1e-6).

#define B_   32
#define C_   768
#define HW_  1024
#define CHW_ (C_ * HW_)          // 786432
#define EPS_NORM 1e-6f
#define EPS_COS  1e-12f

using f32x4  = __attribute__((ext_vector_type(4))) float;
using bf16x8 = __attribute__((ext_vector_type(8))) short;   // 8 bf16 = 4 VGPRs

__device__ inline unsigned short f2bf(float f) {
    union { float f; unsigned u; } v; v.f = f;
    unsigned u = v.u;
    u += 0x7fffu + ((u >> 16) & 1u);        // round-to-nearest-even
    return (unsigned short)(u >> 16);
}

// async global->LDS, 16 B per lane. LDS dst is wave-uniform base + lane*16.
__device__ __forceinline__ void load16_lds(const unsigned short* g, short* l) {
    __builtin_amdgcn_global_load_lds(
        (const __attribute__((address_space(1))) unsigned int*)g,
        (__attribute__((address_space(3))) unsigned int*)l,
        16, 0, 0);
}

// ---------------------------------------------------------------------------
// K1: cast first 1536 rows of W_in (fp32) -> bf16. 1536*768 elems, 4/thread.
// ---------------------------------------------------------------------------
__global__ void wconv_kernel(const float* __restrict__ W, unsigned short* __restrict__ Wbf) {
    const int i = blockIdx.x * 256 + threadIdx.x;     // quad index, 0..294911
    const float4 v = reinterpret_cast<const float4*>(W)[i];
    ushort4 o;
    o.x = f2bf(v.x); o.y = f2bf(v.y); o.z = f2bf(v.z); o.w = f2bf(v.w);
    reinterpret_cast<ushort4*>(Wbf)[i] = o;
}

// ---------------------------------------------------------------------------
// K2: channel sum-of-squares, float4 loads (1 KB/wave-inst).
// grid (24 c-chunks of 32, 32 b), block 256: thread owns 4 hw columns,
// loops 32 c rows, 4 atomicAdd at end. ssum zeroed by memset.
// ---------------------------------------------------------------------------
__global__ void sumsq_kernel(const float* __restrict__ X, float* __restrict__ ssum) {
    const int b  = blockIdx.y;
    const int c0 = blockIdx.x * 32;
    const int t  = threadIdx.x;                       // hw quad 0..255
    const float4* xp = reinterpret_cast<const float4*>(X + (size_t)b * CHW_ + (size_t)c0 * HW_) + t;
    float4 s = {0.f, 0.f, 0.f, 0.f};
    #pragma unroll 8
    for (int c = 0; c < 32; ++c) {
        float4 v = xp[c * 256];
        s.x += v.x * v.x; s.y += v.y * v.y; s.z += v.z * v.z; s.w += v.w * v.w;
    }
    float* dst = ssum + b * HW_ + t * 4;
    atomicAdd(dst + 0, s.x);
    atomicAdd(dst + 1, s.y);
    atomicAdd(dst + 2, s.z);
    atomicAdd(dst + 3, s.w);
}

// ---------------------------------------------------------------------------
// K3: Xn_t[b][hw][c] = bf16( X[b][c][hw] * rsqrt(ssum/768 + eps) )
// 64x64 tile transpose through LDS. grid (16 hw, 12 c, 32 b), block 256.
// Pad 78 shorts (156 B): transpose-phase reads land on 16 bank-groups,
// ~2-way aliasing (free) vs 4-way at pad 72.
// ---------------------------------------------------------------------------
__global__ __launch_bounds__(256) void xnt_kernel(const float* __restrict__ X,
                                                  const float* __restrict__ ssum,
                                                  unsigned short* __restrict__ Xnt) {
    const int b   = blockIdx.z;
    const int c0  = blockIdx.y * 64;
    const int hw0 = blockIdx.x * 64;
    const int tid = threadIdx.x;
    __shared__ short T[64][78];

    #pragma unroll
    for (int it = 0; it < 4; ++it) {
        int q  = it * 256 + tid;        // 0..1023
        int r  = q >> 4;                // c row in tile
        int c4 = (q & 15) * 4;          // hw col in tile
        const float4 x = *reinterpret_cast<const float4*>(
            X + (size_t)b * CHW_ + (size_t)(c0 + r) * HW_ + hw0 + c4);
        const float4 s = *reinterpret_cast<const float4*>(ssum + b * HW_ + hw0 + c4);
        ushort4 o;
        o.x = f2bf(x.x * rsqrtf(s.x * (1.f / 768.f) + EPS_NORM));
        o.y = f2bf(x.y * rsqrtf(s.y * (1.f / 768.f) + EPS_NORM));
        o.z = f2bf(x.z * rsqrtf(s.z * (1.f / 768.f) + EPS_NORM));
        o.w = f2bf(x.w * rsqrtf(s.w * (1.f / 768.f) + EPS_NORM));
        *reinterpret_cast<ushort4*>(&T[r][c4]) = o;
    }
    __syncthreads();
    #pragma unroll
    for (int it = 0; it < 2; ++it) {
        int q  = it * 256 + tid;        // 0..511
        int rp = q >> 3;                // hw row
        int cc = (q & 7) * 8;           // c chunk
        __align__(16) unsigned short tmp[8];
        #pragma unroll
        for (int j = 0; j < 8; ++j) tmp[j] = (unsigned short)T[cc + j][rp];
        *reinterpret_cast<uint4*>(
            Xnt + (size_t)b * CHW_ + (size_t)(hw0 + rp) * C_ + c0 + cc) =
            *reinterpret_cast<const uint4*>(tmp);
    }
}

// ---------------------------------------------------------------------------
// K4: dual-tile GEMM + fused row reductions. BK=64 (12 k-steps, half the
// barrier drains of BK=32; 12 DMA loads in flight per phase).
// LDS rows 128 B unpadded; chunk c of row r stored at slot c^(r&7).
// grid (8 hw-tiles, 6 c-tiles, 32 b), block 256.
// ---------------------------------------------------------------------------
__global__ __launch_bounds__(256, 2) void gemm_kernel(
        const unsigned short* __restrict__ Wbf,   // [1536][768] bf16
        const unsigned short* __restrict__ Xnt,   // [B][HW][C] bf16
        float* __restrict__ wsA) {
    const int n0   = blockIdx.x * 128;
    const int c0   = blockIdx.y * 128;
    const int b    = blockIdx.z;
    const int tid  = threadIdx.x;
    const int lane = tid & 63;
    const int wave = tid >> 6;
    const int wm   = (wave >> 1) * 64;
    const int wn   = (wave & 1) * 64;
    const int quad = lane >> 4;
    const int l15  = lane & 15;

    __shared__ short sAK[128][64];
    __shared__ short sAV[128][64];
    __shared__ short sB [128][64];

    const f32x4 zero = {0.f, 0.f, 0.f, 0.f};
    f32x4 accK[4][4], accV[4][4];
    #pragma unroll
    for (int i = 0; i < 4; ++i)
        #pragma unroll
        for (int j = 0; j < 4; ++j) { accK[i][j] = zero; accV[i][j] = zero; }

    const size_t wk_base = (size_t)c0 * 768;
    const size_t wv_base = (size_t)(768 + c0) * 768;
    const size_t xb      = (size_t)b * CHW_ + (size_t)n0 * 768;

    // staging map (constant): q = it*256+tid; row = q>>3 (0..127), slot = q&7,
    // global chunk = slot ^ (row&7). 8 consecutive lanes cover one 128-B row.
    size_t goff[4];
    int    lrow[4];
    #pragma unroll
    for (int it = 0; it < 4; ++it) {
        int q   = it * 256 + tid;
        int row = q >> 3;
        int gch = (q & 7) ^ (row & 7);
        goff[it] = (size_t)row * 768 + gch * 8;
        lrow[it] = row & ~7;            // wave-uniform LDS base row
    }

    for (int k0 = 0; k0 < 768; k0 += 64) {
        __syncthreads();
        #pragma unroll
        for (int it = 0; it < 4; ++it) {
            load16_lds(Wbf + wk_base + goff[it] + k0, &sAK[lrow[it]][0]);
            load16_lds(Wbf + wv_base + goff[it] + k0, &sAV[lrow[it]][0]);
            load16_lds(Xnt + xb      + goff[it] + k0, &sB [lrow[it]][0]);
        }
        __syncthreads();

        #pragma unroll
        for (int kh = 0; kh < 2; ++kh) {
            bf16x8 aK[4], aV[4], bF[4];
            #pragma unroll
            for (int i = 0; i < 4; ++i) {
                const int rA = wm + 16 * i + l15;
                const int sA = ((kh * 4 + quad) ^ (rA & 7)) * 8;
                aK[i] = *reinterpret_cast<const bf16x8*>(&sAK[rA][sA]);
                aV[i] = *reinterpret_cast<const bf16x8*>(&sAV[rA][sA]);
                const int rB = wn + 16 * i + l15;
                const int sBo = ((kh * 4 + quad) ^ (rB & 7)) * 8;
                bF[i] = *reinterpret_cast<const bf16x8*>(&sB[rB][sBo]);
            }
            #pragma unroll
            for (int i = 0; i < 4; ++i)
                #pragma unroll
                for (int j = 0; j < 4; ++j) {
                    accK[i][j] = __builtin_amdgcn_mfma_f32_16x16x32_bf16(aK[i], bF[j], accK[i][j], 0, 0, 0);
                    accV[i][j] = __builtin_amdgcn_mfma_f32_16x16x32_bf16(aV[i], bF[j], accV[i][j], 0, 0, 0);
                }
        }
    }

    // epilogue: per (i,r) is one c-row (per quad); reduce over the 64 hw cols
    // this wave owns (4 j-frags x 16 col-lanes), then atomic into wsA.
    #pragma unroll
    for (int i = 0; i < 4; ++i) {
        #pragma unroll
        for (int r = 0; r < 4; ++r) {
            float pd = 0.f, pk = 0.f, pv = 0.f;
            #pragma unroll
            for (int j = 0; j < 4; ++j) {
                float kk = accK[i][j][r], vv = accV[i][j][r];
                pd += kk * vv; pk += kk * kk; pv += vv * vv;
            }
            #pragma unroll
            for (int off = 1; off < 16; off <<= 1) {
                pd += __shfl_xor(pd, off);
                pk += __shfl_xor(pk, off);
                pv += __shfl_xor(pv, off);
            }
            if (l15 == 0) {
                int c = c0 + wm + 16 * i + 4 * quad + r;
                float* dst = wsA + ((size_t)b * C_ + c) * 3;
                atomicAdd(dst + 0, pd);
                atomicAdd(dst + 1, pk);
                atomicAdd(dst + 2, pv);
            }
        }
    }
}

// ---------------------------------------------------------------------------
// K5: out = X * gate. One (b,c) per block (1024 elems = 256 float4):
// gate is block-uniform -> scalar loads, no per-thread index math.
// ---------------------------------------------------------------------------
__global__ void final_kernel(const float* __restrict__ X, const float* __restrict__ wsA,
                             float* __restrict__ out) {
    const int bc = blockIdx.x;                 // b*768 + c, 0..24575
    const float* a = wsA + (size_t)bc * 3;
    const float pd = a[0], pk = a[1], pv = a[2];
    const float A = pd / ((sqrtf(pk) + EPS_COS) * (sqrtf(pv) + EPS_COS));
    const float g = 0.5f * A + 0.5f;
    const size_t i4 = (size_t)bc * 256 + threadIdx.x;
    float4 x = reinterpret_cast<const float4*>(X)[i4];
    float4 o;
    o.x = x.x * g; o.y = x.y * g; o.z = x.z * g; o.w = x.w * g;
    reinterpret_cast<float4*>(out)[i4] = o;
}

// ---------------------------------------------------------------------------
extern "C" void kernel_launch(void* const* d_in, const int* in_sizes, int n_in,
                              void* d_out, int out_size, void* d_ws, size_t ws_size,
                              hipStream_t stream) {
    const float* X = (const float*)d_in[0];   // [32,768,32,32]
    const float* W = (const float*)d_in[1];   // [2304,768]
    float* out = (float*)d_out;

    // workspace layout (bytes):
    //   [0,       294912)   wsA   float[32*768*3]  (dot, nk2, nv2)
    //   [294912,  425984)   ssum  float[32*1024]
    //   [425984,  2785280)  Wbf   bf16[1536*768]
    //   [2785280, 53116928) Xnt   bf16[32][1024][768]
    char* ws = (char*)d_ws;
    float* wsA           = (float*)ws;
    float* ssum          = (float*)(ws + 294912);
    unsigned short* Wbf  = (unsigned short*)(ws + 425984);
    unsigned short* Xnt  = (unsigned short*)(ws + 2785280);

    hipMemsetAsync(ws, 0, 425984, stream);    // zero wsA + ssum

    wconv_kernel<<<dim3(1152),       256, 0, stream>>>(W, Wbf);
    sumsq_kernel<<<dim3(24, 32),     256, 0, stream>>>(X, ssum);
    xnt_kernel  <<<dim3(16, 12, 32), 256, 0, stream>>>(X, ssum, Xnt);
    gemm_kernel <<<dim3(8, 6, 32),   256, 0, stream>>>(Wbf, Xnt, wsA);
    final_kernel<<<dim3(24576),      256, 0, stream>>>(X, wsA, out);
}